// Round 1
// baseline (72.649 us; speedup 1.0000x reference)
//
#include <hip/hip_runtime.h>

#define BATCH 8192
#define DIM 128
#define NCLS 6
#define NPAIRS 15  // 6*5/2

// d_ws layout: float z[NCLS*DIM]; unsigned int counts[NCLS]
// total = 6*128*4 + 6*4 = 3096 bytes

__global__ __launch_bounds__(256) void class_sum_kernel(
    const float* __restrict__ latent,
    const int* __restrict__ label,
    float* __restrict__ gz,
    unsigned int* __restrict__ gcnt,
    int nwaves)
{
    __shared__ float lz[NCLS * DIM];
    __shared__ unsigned int lcnt[NCLS];

    const int tid = threadIdx.x;
    for (int i = tid; i < NCLS * DIM; i += blockDim.x) lz[i] = 0.0f;
    if (tid < NCLS) lcnt[tid] = 0u;
    __syncthreads();

    const int lane = tid & 63;
    const int wid = blockIdx.x * (blockDim.x >> 6) + (tid >> 6);

    for (int row = wid; row < BATCH; row += nwaves) {
        // 64 lanes x float2 = 128 floats = one row, coalesced 512B
        const float2 v = *reinterpret_cast<const float2*>(
            latent + (size_t)row * DIM + lane * 2);
        float ss = v.x * v.x + v.y * v.y;
        // wave-wide sum (64 lanes)
        #pragma unroll
        for (int off = 32; off >= 1; off >>= 1)
            ss += __shfl_xor(ss, off);
        const float rn = 1.0f / sqrtf(ss);   // correctly-rounded path (no rsqrt bias)
        const int lab = label[row];
        atomicAdd(&lz[lab * DIM + lane * 2 + 0], v.x * rn);
        atomicAdd(&lz[lab * DIM + lane * 2 + 1], v.y * rn);
        if (lane == 0) atomicAdd(&lcnt[lab], 1u);
    }
    __syncthreads();

    for (int i = tid; i < NCLS * DIM; i += blockDim.x)
        atomicAdd(&gz[i], lz[i]);
    if (tid < NCLS) atomicAdd(&gcnt[tid], lcnt[tid]);
}

__global__ __launch_bounds__(128) void final_kernel(
    const float* __restrict__ gz,
    const unsigned int* __restrict__ gcnt,
    float* __restrict__ out)
{
    __shared__ float ps[NPAIRS];
    const int tid = threadIdx.x;  // 128 threads, one per dim
    if (tid < NPAIRS) ps[tid] = 0.0f;
    __syncthreads();

    float zi[NCLS];
    #pragma unroll
    for (int c = 0; c < NCLS; ++c) zi[c] = gz[c * DIM + tid];

    int p = 0;
    #pragma unroll
    for (int i = 0; i < NCLS; ++i) {
        #pragma unroll
        for (int j = i + 1; j < NCLS; ++j, ++p) {
            atomicAdd(&ps[p], zi[i] * zi[j]);
        }
    }
    __syncthreads();

    if (tid == 0) {
        float acc = 0.0f;
        int p2 = 0;
        for (int i = 0; i < NCLS; ++i) {
            const float n = (float)gcnt[i];
            const float denom = fmaxf(n * n - n, 1.0f);
            for (int j = i + 1; j < NCLS; ++j, ++p2)
                acc += ps[p2] / denom;
        }
        out[0] = acc / (float)NPAIRS;
    }
}

extern "C" void kernel_launch(void* const* d_in, const int* in_sizes, int n_in,
                              void* d_out, int out_size, void* d_ws, size_t ws_size,
                              hipStream_t stream) {
    const float* latent = (const float*)d_in[0];
    const int* label = (const int*)d_in[1];
    float* out = (float*)d_out;

    float* gz = (float*)d_ws;                          // NCLS*DIM floats
    unsigned int* gcnt = (unsigned int*)(gz + NCLS * DIM);  // NCLS uints

    // zero accumulators (graph-capture-safe)
    hipMemsetAsync(d_ws, 0, (NCLS * DIM) * sizeof(float) + NCLS * sizeof(unsigned int), stream);

    const int nblocks = 64;
    const int nthreads = 256;                          // 4 waves
    const int nwaves = nblocks * (nthreads / 64);      // 256 waves, 32 rows each
    class_sum_kernel<<<nblocks, nthreads, 0, stream>>>(latent, label, gz, gcnt, nwaves);
    final_kernel<<<1, 128, 0, stream>>>(gz, gcnt, out);
}

// Round 2
// 43.969 us; speedup vs baseline: 1.6523x; 1.6523x over previous
//
#include <hip/hip_runtime.h>

#define BATCH 8192
#define DIM 128
#define NCLS 6
#define NPAIRS 15
#define NBLK 128
#define NTHR 512
#define WPB (NTHR / 64)           // 8 waves per block
#define NWAVES (NBLK * WPB)       // 1024 waves
#define NPAIRROWS (BATCH / 2)     // 4096 row-pairs (2 rows per wave-iter)
#define ZLEN (NCLS * DIM)         // 768

// d_ws layout: float gpart[NBLK][ZLEN]; float gcntp[NBLK][NCLS]
// = 128*768*4 + 128*6*4 ≈ 396 KB. Fully rewritten every call (poison-safe).

__global__ __launch_bounds__(NTHR) void class_sum_kernel(
    const float* __restrict__ latent,
    const int* __restrict__ label,
    float* __restrict__ gpart,
    float* __restrict__ gcntp)
{
    __shared__ float lz[WPB][ZLEN];
    __shared__ int   lcnt[WPB][NCLS];

    const int tid  = threadIdx.x;
    const int lane = tid & 63;
    const int w    = tid >> 6;
    const int half = lane >> 5;        // 0 or 1: which row of the pair
    const int hl   = lane & 31;        // lane within 32-lane half
    const int gw   = blockIdx.x * WPB + w;

    float4 acc[NCLS];
    int    cnt[NCLS];
    #pragma unroll
    for (int c = 0; c < NCLS; ++c) { acc[c] = make_float4(0.f, 0.f, 0.f, 0.f); cnt[c] = 0; }

    for (int pair = gw; pair < NPAIRROWS; pair += NWAVES) {
        const int row = pair * 2 + half;
        const float4 v = *reinterpret_cast<const float4*>(
            latent + (size_t)row * DIM + hl * 4);
        float ss = v.x * v.x + v.y * v.y + v.z * v.z + v.w * v.w;
        // reduce within each 32-lane half (one row each)
        #pragma unroll
        for (int off = 16; off >= 1; off >>= 1)
            ss += __shfl_xor(ss, off);
        const float rn = 1.0f / sqrtf(ss);   // correctly-rounded (no rsqrt bias)
        const int lab = label[row];
        #pragma unroll
        for (int c = 0; c < NCLS; ++c) {
            const float m = (lab == c) ? rn : 0.0f;   // predicated, static index
            acc[c].x += v.x * m;  acc[c].y += v.y * m;
            acc[c].z += v.z * m;  acc[c].w += v.w * m;
            cnt[c]   += (hl == 0) ? (int)(lab == c) : 0;
        }
    }

    // fold the two 32-lane halves together
    #pragma unroll
    for (int c = 0; c < NCLS; ++c) {
        acc[c].x += __shfl_xor(acc[c].x, 32);
        acc[c].y += __shfl_xor(acc[c].y, 32);
        acc[c].z += __shfl_xor(acc[c].z, 32);
        acc[c].w += __shfl_xor(acc[c].w, 32);
        cnt[c]   += __shfl_xor(cnt[c], 32);
    }

    if (lane < 32) {
        #pragma unroll
        for (int c = 0; c < NCLS; ++c)
            *reinterpret_cast<float4*>(&lz[w][c * DIM + lane * 4]) = acc[c];
    }
    if (lane == 0) {
        #pragma unroll
        for (int c = 0; c < NCLS; ++c) lcnt[w][c] = cnt[c];
    }
    __syncthreads();

    // block-level reduce across the 8 waves, write per-block partials
    for (int e = tid; e < ZLEN; e += NTHR) {
        float s = 0.f;
        #pragma unroll
        for (int ww = 0; ww < WPB; ++ww) s += lz[ww][e];
        gpart[blockIdx.x * ZLEN + e] = s;
    }
    if (tid < NCLS) {
        int s = 0;
        #pragma unroll
        for (int ww = 0; ww < WPB; ++ww) s += lcnt[ww][tid];
        gcntp[blockIdx.x * NCLS + tid] = (float)s;
    }
}

__global__ __launch_bounds__(1024) void finalize_kernel(
    const float* __restrict__ gpart,
    const float* __restrict__ gcntp,
    float* __restrict__ out)
{
    __shared__ float zz[ZLEN];
    __shared__ float cf[NCLS];
    __shared__ float ps[NPAIRS];
    const int tid = threadIdx.x;

    if (tid < ZLEN) {
        float s = 0.f;
        for (int b = 0; b < NBLK; ++b) s += gpart[b * ZLEN + tid];
        zz[tid] = s;
    } else if (tid < ZLEN + NCLS) {
        const int c = tid - ZLEN;
        float s = 0.f;
        for (int b = 0; b < NBLK; ++b) s += gcntp[b * NCLS + c];
        cf[c] = s;
    } else if (tid < ZLEN + NCLS + NPAIRS) {
        ps[tid - ZLEN - NCLS] = 0.f;
    }
    __syncthreads();

    if (tid < DIM) {
        float zi[NCLS];
        #pragma unroll
        for (int c = 0; c < NCLS; ++c) zi[c] = zz[c * DIM + tid];
        int p = 0;
        #pragma unroll
        for (int i = 0; i < NCLS; ++i) {
            #pragma unroll
            for (int j = i + 1; j < NCLS; ++j, ++p)
                atomicAdd(&ps[p], zi[i] * zi[j]);
        }
    }
    __syncthreads();

    if (tid == 0) {
        float acc = 0.f;
        int p = 0;
        for (int i = 0; i < NCLS; ++i) {
            const float n = cf[i];
            const float denom = fmaxf(n * n - n, 1.0f);
            for (int j = i + 1; j < NCLS; ++j, ++p)
                acc += ps[p] / denom;
        }
        out[0] = acc / (float)NPAIRS;
    }
}

extern "C" void kernel_launch(void* const* d_in, const int* in_sizes, int n_in,
                              void* d_out, int out_size, void* d_ws, size_t ws_size,
                              hipStream_t stream) {
    const float* latent = (const float*)d_in[0];
    const int* label = (const int*)d_in[1];
    float* out = (float*)d_out;

    float* gpart = (float*)d_ws;                 // [NBLK][ZLEN]
    float* gcntp = gpart + NBLK * ZLEN;          // [NBLK][NCLS]

    class_sum_kernel<<<NBLK, NTHR, 0, stream>>>(latent, label, gpart, gcntp);
    finalize_kernel<<<1, 1024, 0, stream>>>(gpart, gcntp, out);
}